// Round 11
// baseline (83.533 us; speedup 1.0000x reference)
//
#include <hip/hip_runtime.h>

// BinaryLinearLayer: C = (sign(X) @ sign(W)) * (relu(alpha)*outer(relu(betta),relu(gamma))).flatten()
// M=8192, K=4096, N=2048.
// fp4 e2m1 (+/-1, 0 exact; unit E8M0 scales) -> mfma_scale_f32_32x32x64_f8f6f4.
// Layout: kslot-major 128-row panels: [panel][kslot 0..127][row 0..127] x 16B.
// GEMM v8: NO LDS, NO barriers. Fragments load global->VGPR directly
// (24 KB/block/K-tile fits L1; L2 serves re-reads), software-pipelined X/Y
// register sets, compiler-managed vmcnt. 4 waves/block, 2 blocks/CU.

#define M_DIM 8192
#define K_DIM 4096
#define N_DIM 2048
#define NTK   (K_DIM / 128)          // 32 K-tiles of 128 k
#define PANEL (128 * 128 * 16)       // 256 KB per 128-row/col panel
#define KSTEP 8192                   // bytes per panel per K-tile

typedef int i32x4 __attribute__((ext_vector_type(4)));
typedef int i32x8 __attribute__((ext_vector_type(8)));
typedef float f32x16 __attribute__((ext_vector_type(16)));

__device__ __forceinline__ unsigned int nib4(float x) {
  // sign(x) as fp4 e2m1 nibble: +1 -> 0x2, -1 -> 0xA, 0 -> 0x0
  unsigned int s = (__float_as_uint(x) >> 28) & 0x8u;
  return x == 0.0f ? 0u : (0x2u | s);
}

__device__ __forceinline__ unsigned int pack8(const float* f) {
  unsigned int p = 0;
#pragma unroll
  for (int j = 0; j < 8; ++j) p |= nib4(f[j]) << (4 * j);
  return p;
}

// ---- binX: X f32 [M][K] -> Xq kslot-major; coalesced via LDS stripe ----
__global__ __launch_bounds__(256) void binX_kernel(
    const float* __restrict__ X, unsigned char* __restrict__ Xq) {
  __shared__ float tile[32][260];
  const int t = threadIdx.x;
  const int rg = blockIdx.x >> 4;
  const int kc = blockIdx.x & 15;
  const int lrow = t >> 6;
  const int col4 = (t & 63) * 4;
#pragma unroll
  for (int i = 0; i < 8; ++i)
    *(float4*)&tile[i * 4 + lrow][col4] =
        *(const float4*)&X[(size_t)(rg * 32 + i * 4 + lrow) * K_DIM + kc * 256 + col4];
  __syncthreads();
  const int s = t >> 5;
  const int r = t & 31;
  float f[32];
#pragma unroll
  for (int q = 0; q < 8; ++q)
    *(float4*)&f[q * 4] = *(const float4*)&tile[r][s * 32 + q * 4];
  uint4 gq;
  gq.x = pack8(f + 0);  gq.y = pack8(f + 8);
  gq.z = pack8(f + 16); gq.w = pack8(f + 24);
  const int row = rg * 32 + r;
  const int kslot = kc * 8 + s;
  unsigned char* dst = Xq + (size_t)(row >> 7) * PANEL +
                       ((size_t)kslot * 128 + (row & 127)) * 16;
  *(uint4*)dst = gq;
}

// ---- binW: W f32 [K][N] -> Wq transpose kslot-major (128-col panels) ----
__global__ __launch_bounds__(256) void binW_kernel(
    const float* __restrict__ W, unsigned char* __restrict__ Wq) {
  __shared__ float tile[32][260];
  const int t = threadIdx.x;
  const int q = blockIdx.x >> 7;
  const int kt = (blockIdx.x >> 3) & 15;
  const int s = blockIdx.x & 7;
#pragma unroll
  for (int i = 0; i < 8; ++i) {
    int row = i * 4 + (t >> 6);
    int col4 = (t & 63) * 4;
    *(float4*)&tile[row][col4] =
        *(const float4*)&W[(size_t)(kt * 256 + s * 32 + row) * N_DIM + q * 256 + col4];
  }
  __syncthreads();
  float f[32];
#pragma unroll
  for (int k = 0; k < 32; ++k) f[k] = tile[k][t];
  uint4 gq;
  gq.x = pack8(f + 0);  gq.y = pack8(f + 8);
  gq.z = pack8(f + 16); gq.w = pack8(f + 24);
  const int n = q * 256 + t;
  const int kslot = kt * 8 + s;
  unsigned char* dst = Wq + (size_t)(n >> 7) * PANEL +
                       ((size_t)kslot * 128 + (n & 127)) * 16;
  *(uint4*)dst = gq;
}

// ---------------- GEMM: C[M][N] = Xq * Wq^T (fp4 MX, unit scales) ----------
// 256x128 block tile, BK=128 (2 kk-phases of 64k), 4 waves (wr,wc in 2x2).
// Wave tile 128x64: 4 A-frags x 2 B-frags per kk. All operands global->VGPR.
__global__ __launch_bounds__(256, 2) void gemm_fp4_kernel(
    const unsigned char* __restrict__ Aq,
    const unsigned char* __restrict__ Bq,
    const float* __restrict__ alpha,
    const float* __restrict__ betta,
    const float* __restrict__ gamma,
    float* __restrict__ C) {
  const int t = threadIdx.x;
  const int lane = t & 63;
  const int l31 = lane & 31;
  const int lhi = lane >> 5;
  const int w = t >> 6;          // 0..3
  const int wr = w >> 1;         // 0..1 (128-row half of 256)
  const int wc = w & 1;          // 0..1 (64-col half of 128)

  // XCD decode: xcd = bid&7 owns bm {4x..4x+3} x all 16 bn (bijective).
  const int bid = blockIdx.x;              // 512 blocks
  const int j = bid >> 3;                  // 0..63
  const int bm = (bid & 7) * 4 + (j & 3);  // 0..31 (256-row tiles)
  const int bn = j >> 2;                   // 0..15 (128-col tiles)
  const int row0 = bm * 256;
  const int col0 = bn * 128;

  // wave-uniform panel base + lane-static offset; per (kt,kk) advance is uniform
  const unsigned char* Apan = Aq + (size_t)(2 * bm + wr) * PANEL +
                              lhi * 2048 + l31 * 16;
  const unsigned char* Bpan = Bq + (size_t)bn * PANEL +
                              lhi * 2048 + (wc * 64 + l31) * 16;

  f32x16 acc[4][2];
#pragma unroll
  for (int fm = 0; fm < 4; ++fm)
#pragma unroll
    for (int fn = 0; fn < 2; ++fn)
#pragma unroll
      for (int r = 0; r < 16; ++r) acc[fm][fn][r] = 0.f;

  // two register fragment sets (X/Y), software-pipelined at kk granularity.
  // i32x8 operand slots: loads write the low 4 regs, top 4 stay zero.
  i32x8 aX[4], aY[4], bX[2], bY[2];
#pragma unroll
  for (int i = 0; i < 4; ++i)
#pragma unroll
    for (int e = 0; e < 8; ++e) { aX[i][e] = 0; aY[i][e] = 0; }
#pragma unroll
  for (int i = 0; i < 2; ++i)
#pragma unroll
    for (int e = 0; e < 8; ++e) { bX[i][e] = 0; bY[i][e] = 0; }

  auto loadX = [&](int kt, int kk) {
    const unsigned char* pa = Apan + (size_t)kt * KSTEP + kk * 4096;
    const unsigned char* pb = Bpan + (size_t)kt * KSTEP + kk * 4096;
#pragma unroll
    for (int fm = 0; fm < 4; ++fm)
      *(i32x4*)&aX[fm] = *(const i32x4*)(pa + fm * 512);
#pragma unroll
    for (int fn = 0; fn < 2; ++fn)
      *(i32x4*)&bX[fn] = *(const i32x4*)(pb + fn * 512);
  };
  auto loadY = [&](int kt, int kk) {
    const unsigned char* pa = Apan + (size_t)kt * KSTEP + kk * 4096;
    const unsigned char* pb = Bpan + (size_t)kt * KSTEP + kk * 4096;
#pragma unroll
    for (int fm = 0; fm < 4; ++fm)
      *(i32x4*)&aY[fm] = *(const i32x4*)(pa + fm * 512);
#pragma unroll
    for (int fn = 0; fn < 2; ++fn)
      *(i32x4*)&bY[fn] = *(const i32x4*)(pb + fn * 512);
  };
  auto mmX = [&]() {
#pragma unroll
    for (int fm = 0; fm < 4; ++fm)
#pragma unroll
      for (int fn = 0; fn < 2; ++fn)
        acc[fm][fn] = __builtin_amdgcn_mfma_scale_f32_32x32x64_f8f6f4(
            aX[fm], bX[fn], acc[fm][fn], 4, 4,   // cbsz=fp4, blgp=fp4
            0, 0x7F7F7F7F, 0, 0x7F7F7F7F);       // unit E8M0 scales
  };
  auto mmY = [&]() {
#pragma unroll
    for (int fm = 0; fm < 4; ++fm)
#pragma unroll
      for (int fn = 0; fn < 2; ++fn)
        acc[fm][fn] = __builtin_amdgcn_mfma_scale_f32_32x32x64_f8f6f4(
            aY[fm], bY[fn], acc[fm][fn], 4, 4,
            0, 0x7F7F7F7F, 0, 0x7F7F7F7F);
  };

  // prologue: fill both sets for K-tile 0
  loadX(0, 0);
  loadY(0, 1);

  // main loop: compute(cur set) while the other set's loads fly.
  // kt = NTK-1 issues prefetches at kt+1 = NTK: reads land in workspace
  // slack (Wq is followed by >8 KB of unused d_ws) and are never consumed.
  for (int kt = 0; kt < NTK; ++kt) {
    mmX();                 // (kt, kk=0); compiler waits vmcnt for aX/bX only
    loadX(kt + 1, 0);      // prefetch next tile kk=0 under mmY
    mmY();                 // (kt, kk=1)
    loadY(kt + 1, 1);      // prefetch next tile kk=1 under next mmX
  }

  // epilogue: scale[col] = relu(alpha)*relu(betta[col/64])*relu(gamma[col%64])
  const float ra = fmaxf(alpha[0], 0.0f);
#pragma unroll
  for (int fn = 0; fn < 2; ++fn) {
    const int col = col0 + wc * 64 + fn * 32 + l31;
    const float sc = ra * fmaxf(betta[col >> 6], 0.0f) * fmaxf(gamma[col & 63], 0.0f);
#pragma unroll
    for (int fm = 0; fm < 4; ++fm) {
      const int rbase = row0 + wr * 128 + fm * 32 + 4 * lhi;
#pragma unroll
      for (int r = 0; r < 16; ++r) {
        const int row = rbase + (r & 3) + 8 * (r >> 2);
        C[(size_t)row * N_DIM + col] = acc[fm][fn][r] * sc;
      }
    }
  }
}

extern "C" void kernel_launch(void* const* d_in, const int* in_sizes, int n_in,
                              void* d_out, int out_size, void* d_ws, size_t ws_size,
                              hipStream_t stream) {
  const float* X = (const float*)d_in[0];      // [8192][4096]
  const float* W = (const float*)d_in[1];      // [4096][2048]
  const float* alpha = (const float*)d_in[2];  // [1]
  const float* betta = (const float*)d_in[3];  // [32]
  const float* gamma = (const float*)d_in[4];  // [64]
  float* out = (float*)d_out;                  // [8192][2048]

  unsigned char* Xq = (unsigned char*)d_ws;                  // 16 MiB
  unsigned char* Wq = Xq + (size_t)(M_DIM / 128) * PANEL;    // 4 MiB
  // (d_ws extends well past Wq: tail prefetch slack is in-bounds)

  binW_kernel<<<1024, 256, 0, stream>>>(W, Wq);
  binX_kernel<<<4096, 256, 0, stream>>>(X, Xq);
  gemm_fp4_kernel<<<(M_DIM / 256) * (N_DIM / 128), 256, 0, stream>>>(
      Xq, Wq, alpha, betta, gamma, out);
}

// Round 12
// 70.984 us; speedup vs baseline: 1.1768x; 1.1768x over previous
//
#include <hip/hip_runtime.h>

// BinaryLinearLayer: C = (sign(X) @ sign(W)) * (relu(alpha)*outer(relu(betta),relu(gamma))).flatten()
// M=8192, K=4096, N=2048.
// fp4 e2m1 (+/-1, 0 exact; unit E8M0 scales) -> mfma_scale_f32_32x32x64_f8f6f4.
// Layout: kslot-major 128-row panels: [panel][kslot 0..127][row 0..127] x 16B.
// GEMM: 256x256 tile, BK=128, 8 waves (wave 128x64), LDS 3x32KB, counted
// vmcnt(4) pipeline (T4), 1 raw barrier/K-tile, nontemporal C stores.

#define M_DIM 8192
#define K_DIM 4096
#define N_DIM 2048
#define NTK   (K_DIM / 128)          // 32 K-tiles of 128 k
#define PANEL (128 * 128 * 16)       // 256 KB per 128-row/col panel
#define KSTEP 8192                   // bytes per panel per K-tile
#define BUFB  32768                  // LDS buf: A0,A1,B0,B1 x 8KB

typedef int i32x4 __attribute__((ext_vector_type(4)));
typedef int i32x8 __attribute__((ext_vector_type(8)));
typedef float f32x16 __attribute__((ext_vector_type(16)));

__device__ __forceinline__ unsigned int nib4(float x) {
  // sign(x) as fp4 e2m1 nibble: +1 -> 0x2, -1 -> 0xA, 0 -> 0x0
  unsigned int s = (__float_as_uint(x) >> 28) & 0x8u;
  return x == 0.0f ? 0u : (0x2u | s);
}

__device__ __forceinline__ unsigned int pack8(const float* f) {
  unsigned int p = 0;
#pragma unroll
  for (int j = 0; j < 8; ++j) p |= nib4(f[j]) << (4 * j);
  return p;
}

__device__ __forceinline__ void gload_lds16(const void* g, void* lds) {
  __builtin_amdgcn_global_load_lds(
      (const __attribute__((address_space(1))) unsigned int*)g,
      (__attribute__((address_space(3))) unsigned int*)lds, 16, 0, 0);
}

// ---- fused binarize: blocks [0,4096) = X path, [4096,5120) = W path ----
__global__ __launch_bounds__(256) void binXW_kernel(
    const float* __restrict__ X, const float* __restrict__ W,
    unsigned char* __restrict__ Xq, unsigned char* __restrict__ Wq) {
  __shared__ float tile[32][260];   // 1040B row stride: 16B-aligned
  const int t = threadIdx.x;
  const int bid = blockIdx.x;

  if (bid < 4096) {
    // X: rg = bid>>4 (32 rows), kc = bid&15 (256-k chunk)
    const int rg = bid >> 4;
    const int kc = bid & 15;
    const int lrow = t >> 6;
    const int col4 = (t & 63) * 4;
#pragma unroll
    for (int i = 0; i < 8; ++i)
      *(float4*)&tile[i * 4 + lrow][col4] =
          *(const float4*)&X[(size_t)(rg * 32 + i * 4 + lrow) * K_DIM + kc * 256 + col4];
    __syncthreads();
    const int s = t >> 5;
    const int r = t & 31;
    float f[32];
#pragma unroll
    for (int q = 0; q < 8; ++q)
      *(float4*)&f[q * 4] = *(const float4*)&tile[r][s * 32 + q * 4];
    uint4 gq;
    gq.x = pack8(f + 0);  gq.y = pack8(f + 8);
    gq.z = pack8(f + 16); gq.w = pack8(f + 24);
    const int row = rg * 32 + r;
    const int kslot = kc * 8 + s;
    unsigned char* dst = Xq + (size_t)(row >> 7) * PANEL +
                         ((size_t)kslot * 128 + (row & 127)) * 16;
    *(uint4*)dst = gq;
  } else {
    // W: q = idx>>7 (256-n stripe), kt = (idx>>3)&15, s = idx&7
    const int idx = bid - 4096;
    const int q = idx >> 7;
    const int kt = (idx >> 3) & 15;
    const int s = idx & 7;
#pragma unroll
    for (int i = 0; i < 8; ++i) {
      int row = i * 4 + (t >> 6);
      int col4 = (t & 63) * 4;
      *(float4*)&tile[row][col4] =
          *(const float4*)&W[(size_t)(kt * 256 + s * 32 + row) * N_DIM + q * 256 + col4];
    }
    __syncthreads();
    float f[32];
#pragma unroll
    for (int k = 0; k < 32; ++k) f[k] = tile[k][t];
    uint4 gq;
    gq.x = pack8(f + 0);  gq.y = pack8(f + 8);
    gq.z = pack8(f + 16); gq.w = pack8(f + 24);
    const int n = q * 256 + t;
    const int kslot = kt * 8 + s;
    unsigned char* dst = Wq + (size_t)(n >> 7) * PANEL +
                         ((size_t)kslot * 128 + (n & 127)) * 16;
    *(uint4*)dst = gq;
  }
}

// ---------------- GEMM: C[M][N] = Xq * Wq^T (fp4 MX, unit scales) ----------
// 256x256 tile, 8 waves (wr 0..1 x wc 0..3), wave 128x64 = 4x2 frags.
// 3-deep LDS, stage 2 tiles ahead, counted vmcnt(4) (T4), nt C stores.
__global__ __launch_bounds__(512, 2) void gemm_fp4_kernel(
    const unsigned char* __restrict__ Aq,
    const unsigned char* __restrict__ Bq,
    const float* __restrict__ alpha,
    const float* __restrict__ betta,
    const float* __restrict__ gamma,
    float* __restrict__ C) {
  __shared__ __align__(16) unsigned char smem[3 * BUFB];  // 96 KB

  const int t = threadIdx.x;
  const int lane = t & 63;
  const int l31 = lane & 31;
  const int lhi = lane >> 5;
  const int w = t >> 6;          // 0..7
  const int wr = w >> 2;         // 0..1 (128-row half of 256)
  const int wc = w & 3;          // 0..3 (64-col quarter of 256)

  // XCD decode: xcd = bid&7 owns bm {4x..4x+3} x all 8 bn (bijective, 256 blks)
  const int bid = blockIdx.x;
  const int j = bid >> 3;                  // 0..31
  const int bm = (bid & 7) * 4 + (j & 3);  // 0..31 (256-row tiles)
  const int bn = j >> 2;                   // 0..7  (256-col tiles)
  const int row0 = bm * 256;
  const int col0 = bn * 256;

  const unsigned char* Asrc0 = Aq + (size_t)(2 * bm) * PANEL;
  const unsigned char* Asrc1 = Asrc0 + PANEL;
  const unsigned char* Bsrc0 = Bq + (size_t)(2 * bn) * PANEL;
  const unsigned char* Bsrc1 = Bsrc0 + PANEL;

  f32x16 acc[4][2];
#pragma unroll
  for (int fm = 0; fm < 4; ++fm)
#pragma unroll
    for (int fn = 0; fn < 2; ++fn)
#pragma unroll
      for (int r = 0; r < 16; ++r) acc[fm][fn][r] = 0.f;

  // operand tuples: top halves zero (fp4 uses low 4 regs)
  i32x8 a8[4], b8[2];
#pragma unroll
  for (int i = 0; i < 4; ++i)
#pragma unroll
    for (int e = 0; e < 8; ++e) a8[i][e] = 0;
#pragma unroll
  for (int i = 0; i < 2; ++i)
#pragma unroll
    for (int e = 0; e < 8; ++e) b8[i][e] = 0;

  // stage one K-tile (A 16KB + B 16KB) into buf: 4 gload_lds16 per thread
  auto stage = [&](int kt, unsigned char* buf) {
    const size_t ko = (size_t)kt * KSTEP;
    gload_lds16(Asrc0 + ko + t * 16, buf + t * 16);
    gload_lds16(Asrc1 + ko + t * 16, buf + 8192 + t * 16);
    gload_lds16(Bsrc0 + ko + t * 16, buf + 16384 + t * 16);
    gload_lds16(Bsrc1 + ko + t * 16, buf + 24576 + t * 16);
  };

  auto compute = [&](const unsigned char* buf) {
    const unsigned char* pA = buf + wr * 8192;
    const unsigned char* pB = buf + 16384 + (wc >> 1) * 8192;
    const int cb = (wc & 1) * 64;
#pragma unroll
    for (int kk = 0; kk < 2; ++kk) {
      const int g = kk * 2 + lhi;  // kslot 0..3
#pragma unroll
      for (int fm = 0; fm < 4; ++fm)
        *(i32x4*)&a8[fm] = *(const i32x4*)&pA[(g * 128 + fm * 32 + l31) * 16];
#pragma unroll
      for (int fn = 0; fn < 2; ++fn)
        *(i32x4*)&b8[fn] = *(const i32x4*)&pB[(g * 128 + cb + fn * 32 + l31) * 16];
      __builtin_amdgcn_s_setprio(1);
#pragma unroll
      for (int fm = 0; fm < 4; ++fm)
#pragma unroll
        for (int fn = 0; fn < 2; ++fn)
          acc[fm][fn] = __builtin_amdgcn_mfma_scale_f32_32x32x64_f8f6f4(
              a8[fm], b8[fn], acc[fm][fn], 4, 4,   // cbsz=fp4, blgp=fp4
              0, 0x7F7F7F7F, 0, 0x7F7F7F7F);       // unit E8M0 scales
      __builtin_amdgcn_s_setprio(0);
    }
  };

  unsigned char* P0 = smem;
  unsigned char* P1 = smem + BUFB;
  unsigned char* P2 = smem + 2 * BUFB;

  // prologue: 2 tiles in flight
  stage(0, P0);
  stage(1, P1);

  for (int kt = 0; kt < NTK - 1; ++kt) {
    // T4: wait until <=4 loads outstanding (stage(kt) done, stage(kt+1)
    // still flying). NEVER vmcnt(0) in the main loop.
    asm volatile("s_waitcnt vmcnt(4)" ::: "memory");
    __builtin_amdgcn_s_barrier();          // publishes stage(kt) to all waves
    __builtin_amdgcn_sched_barrier(0);     // no ds_read hoisted above barrier
    if (kt + 2 < NTK) stage(kt + 2, P2);   // P2 = buf(kt-1): done reading
    compute(P0);
    unsigned char* tmp = P0; P0 = P1; P1 = P2; P2 = tmp;
  }
  // peeled last tile: full drain
  asm volatile("s_waitcnt vmcnt(0)" ::: "memory");
  __builtin_amdgcn_s_barrier();
  __builtin_amdgcn_sched_barrier(0);
  compute(P0);

  // epilogue: scale[col] = relu(alpha)*relu(betta[col/64])*relu(gamma[col%64])
  // nontemporal stores: C is write-once, keep operand panels resident in L2.
  const float ra = fmaxf(alpha[0], 0.0f);
#pragma unroll
  for (int fn = 0; fn < 2; ++fn) {
    const int col = col0 + wc * 64 + fn * 32 + l31;
    const float sc = ra * fmaxf(betta[col >> 6], 0.0f) * fmaxf(gamma[col & 63], 0.0f);
#pragma unroll
    for (int fm = 0; fm < 4; ++fm) {
      const int rbase = row0 + wr * 128 + fm * 32 + 4 * lhi;
#pragma unroll
      for (int r = 0; r < 16; ++r) {
        const int row = rbase + (r & 3) + 8 * (r >> 2);
        __builtin_nontemporal_store(acc[fm][fn][r] * sc,
                                    &C[(size_t)row * N_DIM + col]);
      }
    }
  }
}

extern "C" void kernel_launch(void* const* d_in, const int* in_sizes, int n_in,
                              void* d_out, int out_size, void* d_ws, size_t ws_size,
                              hipStream_t stream) {
  const float* X = (const float*)d_in[0];      // [8192][4096]
  const float* W = (const float*)d_in[1];      // [4096][2048]
  const float* alpha = (const float*)d_in[2];  // [1]
  const float* betta = (const float*)d_in[3];  // [32]
  const float* gamma = (const float*)d_in[4];  // [64]
  float* out = (float*)d_out;                  // [8192][2048]

  unsigned char* Xq = (unsigned char*)d_ws;                  // 16 MiB
  unsigned char* Wq = Xq + (size_t)(M_DIM / 128) * PANEL;    // 4 MiB

  binXW_kernel<<<5120, 256, 0, stream>>>(X, W, Xq, Wq);
  gemm_fp4_kernel<<<(M_DIM / 256) * (N_DIM / 256), 512, 0, stream>>>(
      Xq, Wq, alpha, betta, gamma, out);
}